// Round 10
// baseline (233.187 us; speedup 1.0000x reference)
//
#include <hip/hip_runtime.h>
#include <hip/hip_bf16.h>

#define BB 32
#define LL 512
#define DD 1024
#define NHD 1024
#define EE 128
#define NCOL 120
#define KTOK 4
#define TOPKN 6
#define MROWS (BB * NCOL)   // 3840

typedef __attribute__((ext_vector_type(8))) _Float16 f16x8;
typedef __attribute__((ext_vector_type(4))) float f32x4;

__device__ inline ushort f2h(float x) {
    _Float16 h = (_Float16)x;              // RNE via v_cvt_f16_f32
    union { _Float16 h; ushort u; } c;
    c.h = h;
    return c.u;
}

// ---------------------------------------------------------------------------
// K1: ee_h[b,e,:] = fp16( sum_k q_enc[b, tok[e,k], :] )  + folded init duty
// ---------------------------------------------------------------------------
__global__ __launch_bounds__(256) void ee_kernel(const float* __restrict__ q,
                                                 const int* __restrict__ tok,
                                                 ushort* __restrict__ ee,
                                                 float* __restrict__ att,
                                                 const float* __restrict__ b_o2,
                                                 float* __restrict__ H,
                                                 const float* __restrict__ b_t1) {
    int be = blockIdx.x;
    int b  = be >> 7;
    int e  = be & 127;
    int t  = threadIdx.x;

    if (be < 15) {
        att[be * 256 + t] = b_o2[0];
    } else if (be < 15 + 128) {
        int j = (be - 15) * 256 + t;
        H[j] = b_t1[j & (NHD - 1)];
    }

    const float* qb = q + (size_t)b * LL * DD;
    int t0 = tok[e * KTOK + 0];
    int t1 = tok[e * KTOK + 1];
    int t2 = tok[e * KTOK + 2];
    int t3 = tok[e * KTOK + 3];
    int f = t * 4;
    float4 a = *(const float4*)(qb + (size_t)t0 * DD + f);
    float4 bv = *(const float4*)(qb + (size_t)t1 * DD + f);
    float4 c = *(const float4*)(qb + (size_t)t2 * DD + f);
    float4 d = *(const float4*)(qb + (size_t)t3 * DD + f);
    ushort4 o;
    o.x = f2h(a.x + bv.x + c.x + d.x);
    o.y = f2h(a.y + bv.y + c.y + d.y);
    o.z = f2h(a.z + bv.z + c.z + d.z);
    o.w = f2h(a.w + bv.w + c.w + d.w);
    *(ushort4*)(ee + (size_t)be * DD + f) = o;
}

// ---------------------------------------------------------------------------
// Pack W [D][N] fp32 -> fp16 MFMA B-fragment order (3 weights in one launch)
// ---------------------------------------------------------------------------
__global__ __launch_bounds__(256) void pack_w_kernel(
    const float* __restrict__ W0, const float* __restrict__ W1f,
    const float* __restrict__ W2f, ushort* __restrict__ pk0,
    ushort* __restrict__ pk1, ushort* __restrict__ pk2) {
    const float* W = blockIdx.y == 0 ? W0 : (blockIdx.y == 1 ? W1f : W2f);
    ushort* pk     = blockIdx.y == 0 ? pk0 : (blockIdx.y == 1 ? pk1 : pk2);
    int idx = blockIdx.x * 256 + threadIdx.x;    // 0 .. 131071
    int l  = idx & 63;
    int kb = (idx >> 6) & 31;
    int nb = idx >> 11;
    int row = kb * 32 + (l >> 4) * 8;
    int col = nb * 16 + (l & 15);
    ushort o[8];
#pragma unroll
    for (int j = 0; j < 8; ++j)
        o[j] = f2h(W[(size_t)(row + j) * NHD + col]);
    ulong2 v;
    v.x = ((ulong)o[0]) | ((ulong)o[1] << 16) | ((ulong)o[2] << 32) | ((ulong)o[3] << 48);
    v.y = ((ulong)o[4]) | ((ulong)o[5] << 16) | ((ulong)o[6] << 32) | ((ulong)o[7] << 48);
    *(ulong2*)(pk + (size_t)idx * 8) = v;
}

// ---------------------------------------------------------------------------
// Pipelined fragment GEMM core: 32x32 wave tile, depth-3 register pipeline.
// Stage vars are named (no runtime indexing -> stay in VGPRs).
// ---------------------------------------------------------------------------
#define DEF_MFMA(A0, A1, B0, B1)                                                \
    {                                                                           \
        acc00 = __builtin_amdgcn_mfma_f32_16x16x32_f16(A0, B0, acc00, 0, 0, 0); \
        acc01 = __builtin_amdgcn_mfma_f32_16x16x32_f16(A0, B1, acc01, 0, 0, 0); \
        acc10 = __builtin_amdgcn_mfma_f32_16x16x32_f16(A1, B0, acc10, 0, 0, 0); \
        acc11 = __builtin_amdgcn_mfma_f32_16x16x32_f16(A1, B1, acc11, 0, 0, 0); \
    }

// one phase of K=1024 (32 steps of 32), pointers ar0/ar1 (A rows), W (packed B)
#define GEMM_PIPE(ar0, ar1, W)                                                  \
    {                                                                           \
        const ushort* a0p = (ar0);                                              \
        const ushort* a1p = (ar1);                                              \
        const ushort* wp  = (W);                                                \
        _LD(Aa0, Aa1, Ba0, Ba1, 0)                                              \
        _LD(Ab0, Ab1, Bb0, Bb1, 1)                                              \
        _LD(Ac0, Ac1, Bc0, Bc1, 2)                                              \
        _Pragma("unroll 1")                                                     \
        for (int kb = 0; kb < 27; kb += 3) {                                    \
            DEF_MFMA(Aa0, Aa1, Ba0, Ba1) _LD(Aa0, Aa1, Ba0, Ba1, kb + 3)        \
            DEF_MFMA(Ab0, Ab1, Bb0, Bb1) _LD(Ab0, Ab1, Bb0, Bb1, kb + 4)        \
            DEF_MFMA(Ac0, Ac1, Bc0, Bc1) _LD(Ac0, Ac1, Bc0, Bc1, kb + 5)        \
        }                                                                       \
        DEF_MFMA(Aa0, Aa1, Ba0, Ba1) _LD(Aa0, Aa1, Ba0, Ba1, 30)                \
        DEF_MFMA(Ab0, Ab1, Bb0, Bb1) _LD(Ab0, Ab1, Bb0, Bb1, 31)                \
        DEF_MFMA(Ac0, Ac1, Bc0, Bc1)                                            \
        DEF_MFMA(Aa0, Aa1, Ba0, Ba1)                                            \
        DEF_MFMA(Ab0, Ab1, Bb0, Bb1)                                            \
    }

#define _LD(A0, A1, B0, B1, kb)                                                 \
    {                                                                           \
        A0 = *(const f16x8*)(a0p + (kb) * 32 + koff);                           \
        A1 = *(const f16x8*)(a1p + (kb) * 32 + koff);                           \
        B0 = *(const f16x8*)(wp + (((size_t)nb0 * 32 + (kb)) * 64 + l) * 8);    \
        B1 = *(const f16x8*)(wp + (((size_t)(nb0 + 1) * 32 + (kb)) * 64 + l) * 8); \
    }

// ---------------------------------------------------------------------------
// GEMM1: fused[r,f] = fp16( ee[b,ci[i],:].Wc[:,f] + ee[b,ti[i],:].Wt[:,f]
//                            + bc[f] + bt[f] ),  r = b*120+i
// Block tile 64x64, 4 waves (2x2), wave tile 32x32. 3840 waves total.
// ---------------------------------------------------------------------------
__global__ __launch_bounds__(256) void gemm1_kernel(
    const ushort* __restrict__ ee, const int* __restrict__ ci, const int* __restrict__ ti,
    const ushort* __restrict__ Wc_pk, const ushort* __restrict__ Wt_pk,
    const float* __restrict__ bc, const float* __restrict__ bt,
    ushort* __restrict__ fused) {
    int t = threadIdx.x;
    int l = t & 63;
    int w = t >> 6;
    int wm = w >> 1, wn = w & 1;
    int row0 = blockIdx.x * 64 + wm * 32;
    int col0 = blockIdx.y * 64 + wn * 32;
    int nb0  = col0 >> 4;
    int koff = (l >> 4) * 8;

    const ushort* arow0[2];
    const ushort* arow1[2];
#pragma unroll
    for (int m = 0; m < 2; ++m) {
        int r = row0 + m * 16 + (l & 15);
        int b = r / NCOL;
        int i = r - b * NCOL;
        arow0[m] = ee + ((size_t)(b * EE + ci[i])) * DD;
        arow1[m] = ee + ((size_t)(b * EE + ti[i])) * DD;
    }

    f32x4 acc00 = {}, acc01 = {}, acc10 = {}, acc11 = {};
    f16x8 Aa0, Aa1, Ba0, Ba1, Ab0, Ab1, Bb0, Bb1, Ac0, Ac1, Bc0, Bc1;

    GEMM_PIPE(arow0[0], arow0[1], Wc_pk)
    GEMM_PIPE(arow1[0], arow1[1], Wt_pk)

    float badd[2];
#pragma unroll
    for (int n = 0; n < 2; ++n) {
        int c = col0 + n * 16 + (l & 15);
        badd[n] = bc[c] + bt[c];
    }
    int rlane = (l >> 4) * 4;
    f32x4 accm[2][2] = {{acc00, acc01}, {acc10, acc11}};
#pragma unroll
    for (int m = 0; m < 2; ++m)
#pragma unroll
        for (int n = 0; n < 2; ++n) {
            int c = col0 + n * 16 + (l & 15);
#pragma unroll
            for (int j = 0; j < 4; ++j) {
                int r = row0 + m * 16 + rlane + j;
                fused[(size_t)r * NHD + c] = f2h(accm[m][n][j] + badd[n]);
            }
        }
}

// ---------------------------------------------------------------------------
// GEMM2: h = relu(fused @ W_o1 + b_o1); att[r] += h . W_o2   (h in regs only)
// Same 32x32 wave tile + depth-3 pipeline; fused epilogue.
// ---------------------------------------------------------------------------
__global__ __launch_bounds__(256) void gemm2_kernel(
    const ushort* __restrict__ fused, const ushort* __restrict__ W1_pk,
    const float* __restrict__ b1, const float* __restrict__ W2,
    float* __restrict__ att) {
    int t = threadIdx.x;
    int l = t & 63;
    int w = t >> 6;
    int wm = w >> 1, wn = w & 1;
    int row0 = blockIdx.x * 64 + wm * 32;
    int col0 = blockIdx.y * 64 + wn * 32;
    int nb0  = col0 >> 4;
    int koff = (l >> 4) * 8;

    const ushort* arow[2];
#pragma unroll
    for (int m = 0; m < 2; ++m)
        arow[m] = fused + (size_t)(row0 + m * 16 + (l & 15)) * NHD;

    f32x4 acc00 = {}, acc01 = {}, acc10 = {}, acc11 = {};
    f16x8 Aa0, Aa1, Ba0, Ba1, Ab0, Ab1, Bb0, Bb1, Ac0, Ac1, Bc0, Bc1;

    GEMM_PIPE(arow[0], arow[1], W1_pk)

    float bo[2], wo[2];
#pragma unroll
    for (int n = 0; n < 2; ++n) {
        int c = col0 + n * 16 + (l & 15);
        bo[n] = b1[c];
        wo[n] = W2[c];
    }
    int rlane = (l >> 4) * 4;
    f32x4 accm[2][2] = {{acc00, acc01}, {acc10, acc11}};
#pragma unroll
    for (int m = 0; m < 2; ++m) {
#pragma unroll
        for (int j = 0; j < 4; ++j) {
            float p = 0.f;
#pragma unroll
            for (int n = 0; n < 2; ++n) {
                float h = fmaxf(accm[m][n][j] + bo[n], 0.f);
                p = fmaf(h, wo[n], p);
            }
            p += __shfl_xor(p, 1);
            p += __shfl_xor(p, 2);
            p += __shfl_xor(p, 4);
            p += __shfl_xor(p, 8);
            if ((l & 15) == 0)
                atomicAdd(&att[row0 + m * 16 + rlane + j], p);
        }
    }
}

// ---------------------------------------------------------------------------
// K5a: H[b,f] += cls[b, k-chunk] @ W_t1[k-chunk, f-chunk]   (fp32, atomics)
// ---------------------------------------------------------------------------
__global__ __launch_bounds__(256) void topk_h_kernel(const float* __restrict__ q,
                                                     const float* __restrict__ W1,
                                                     float* __restrict__ H) {
    __shared__ float cls[BB][128];
    __shared__ float wsh[128][17];
    int f0 = blockIdx.x * 16;
    int k0 = blockIdx.y * 128;
    int t = threadIdx.x;
#pragma unroll
    for (int m = 0; m < 16; ++m) {
        int idx = t + m * 256;              // 0..4095
        int b = idx >> 7, d = idx & 127;
        cls[b][d] = q[(size_t)b * LL * DD + k0 + d];
    }
#pragma unroll
    for (int m = 0; m < 8; ++m) {
        int idx = t + m * 256;              // 0..2047
        int r = idx >> 4, c = idx & 15;
        wsh[r][c] = W1[(size_t)(k0 + r) * NHD + f0 + c];
    }
    __syncthreads();
    int f = t & 15;
    int b0 = t >> 4;                        // 0..15
#pragma unroll
    for (int h = 0; h < 2; ++h) {
        int b = b0 + h * 16;
        float s = 0.f;
#pragma unroll 8
        for (int d = 0; d < 128; ++d)
            s = fmaf(cls[b][d], wsh[d][f], s);
        atomicAdd(&H[(size_t)b * NHD + f0 + f], s);
    }
}

// ---------------------------------------------------------------------------
// K5b: topk[b,:] = sigmoid(relu(H[b,:]) @ W_t2 + b_t2)
// ---------------------------------------------------------------------------
__global__ __launch_bounds__(256) void topk_out_kernel(
    const float* __restrict__ H, const float* __restrict__ W2,
    const float* __restrict__ b2, float* __restrict__ outp) {
    __shared__ float red[4][TOPKN];
    int b = blockIdx.x;
    int t = threadIdx.x;
    float part[TOPKN] = {};
#pragma unroll
    for (int m = 0; m < 4; ++m) {
        int f = t + m * 256;
        float h = fmaxf(H[(size_t)b * NHD + f], 0.f);
#pragma unroll
        for (int k = 0; k < TOPKN; ++k)
            part[k] = fmaf(h, W2[f * TOPKN + k], part[k]);
    }
#pragma unroll
    for (int k = 0; k < TOPKN; ++k) {
        float v = part[k];
        for (int off = 1; off < 64; off <<= 1) v += __shfl_xor(v, off);
        part[k] = v;
    }
    int wave = t >> 6, lane = t & 63;
    if (lane == 0)
#pragma unroll
        for (int k = 0; k < TOPKN; ++k) red[wave][k] = part[k];
    __syncthreads();
    if (t == 0)
#pragma unroll
        for (int k = 0; k < TOPKN; ++k) {
            float s = red[0][k] + red[1][k] + red[2][k] + red[3][k] + b2[k];
            outp[b * TOPKN + k] = 1.f / (1.f + __expf(-s));
        }
}

// ---------------------------------------------------------------------------
extern "C" void kernel_launch(void* const* d_in, const int* in_sizes, int n_in,
                              void* d_out, int out_size, void* d_ws, size_t ws_size,
                              hipStream_t stream) {
    const float* q_enc   = (const float*)d_in[0];
    const int*   etok    = (const int*)  d_in[1];
    const int*   ci      = (const int*)  d_in[2];
    const int*   ti      = (const int*)  d_in[3];
    const float* W_table = (const float*)d_in[4];
    const float* b_table = (const float*)d_in[5];
    const float* W_col   = (const float*)d_in[6];
    const float* b_col   = (const float*)d_in[7];
    const float* W_o1    = (const float*)d_in[8];
    const float* b_o1    = (const float*)d_in[9];
    const float* W_o2    = (const float*)d_in[10];
    const float* b_o2    = (const float*)d_in[11];
    const float* W_t1    = (const float*)d_in[12];
    const float* b_t1    = (const float*)d_in[13];
    const float* W_t2    = (const float*)d_in[14];
    const float* b_t2    = (const float*)d_in[15];

    float* outp = (float*)d_out;
    float* att  = outp;            // 3840
    float* topk = outp + MROWS;    // 192

    // workspace layout (bytes)
    char* ws = (char*)d_ws;
    ushort* ee_h    = (ushort*)(ws);                          // 4,194,304 fp16
    ushort* fused   = (ushort*)(ws + 8388608);                // 3,932,160 fp16
    ushort* Wc_pk   = (ushort*)(ws + 16252928);               // 1,048,576 fp16
    ushort* Wt_pk   = (ushort*)(ws + 18350080);               // 1,048,576 fp16
    ushort* Wo1_pk  = (ushort*)(ws + 20447232);               // 1,048,576 fp16
    float*  H       = (float*) (ws + 22544384);               // 32,768 f32

    hipLaunchKernelGGL(ee_kernel, dim3(BB * EE), dim3(256), 0, stream,
                       q_enc, etok, ee_h, att, b_o2, H, b_t1);
    hipLaunchKernelGGL(pack_w_kernel, dim3(512, 3), dim3(256), 0, stream,
                       W_col, W_table, W_o1, Wc_pk, Wt_pk, Wo1_pk);
    hipLaunchKernelGGL(gemm1_kernel, dim3(MROWS / 64, NHD / 64), dim3(256), 0, stream,
                       ee_h, ci, ti, Wc_pk, Wt_pk, b_col, b_table, fused);
    hipLaunchKernelGGL(gemm2_kernel, dim3(MROWS / 64, NHD / 64), dim3(256), 0, stream,
                       fused, Wo1_pk, b_o1, W_o2, att);
    hipLaunchKernelGGL(topk_h_kernel, dim3(64, 8), dim3(256), 0, stream, q_enc, W_t1, H);
    hipLaunchKernelGGL(topk_out_kernel, dim3(BB), dim3(256), 0, stream, H, W_t2, b_t2, topk);
}

// Round 13
// 215.832 us; speedup vs baseline: 1.0804x; 1.0804x over previous
//
#include <hip/hip_runtime.h>
#include <hip/hip_bf16.h>

#define BB 32
#define LL 512
#define DD 1024
#define NHD 1024
#define EE 128
#define NCOL 120
#define KTOK 4
#define TOPKN 6
#define MROWS (BB * NCOL)   // 3840
#define NKB1 64             // gemm1 K-steps (2 phases x 32)
#define NKB2 32             // gemm2 K-steps

typedef __attribute__((ext_vector_type(8))) _Float16 f16x8;
typedef __attribute__((ext_vector_type(4))) float f32x4;

__device__ inline ushort f2h(float x) {
    _Float16 h = (_Float16)x;              // RNE via v_cvt_f16_f32
    union { _Float16 h; ushort u; } c;
    c.h = h;
    return c.u;
}

// ---------------------------------------------------------------------------
// K1: ee_h[b,e,:] = fp16( sum_k q_enc[b, tok[e,k], :] )  + folded init duty
// ---------------------------------------------------------------------------
__global__ __launch_bounds__(256) void ee_kernel(const float* __restrict__ q,
                                                 const int* __restrict__ tok,
                                                 ushort* __restrict__ ee,
                                                 float* __restrict__ att,
                                                 const float* __restrict__ b_o2,
                                                 float* __restrict__ H,
                                                 const float* __restrict__ b_t1) {
    int be = blockIdx.x;
    int b  = be >> 7;
    int e  = be & 127;
    int t  = threadIdx.x;

    if (be < 15) {
        att[be * 256 + t] = b_o2[0];
    } else if (be < 15 + 128) {
        int j = (be - 15) * 256 + t;
        H[j] = b_t1[j & (NHD - 1)];
    }

    const float* qb = q + (size_t)b * LL * DD;
    int t0 = tok[e * KTOK + 0];
    int t1 = tok[e * KTOK + 1];
    int t2 = tok[e * KTOK + 2];
    int t3 = tok[e * KTOK + 3];
    int f = t * 4;
    float4 a = *(const float4*)(qb + (size_t)t0 * DD + f);
    float4 bv = *(const float4*)(qb + (size_t)t1 * DD + f);
    float4 c = *(const float4*)(qb + (size_t)t2 * DD + f);
    float4 d = *(const float4*)(qb + (size_t)t3 * DD + f);
    ushort4 o;
    o.x = f2h(a.x + bv.x + c.x + d.x);
    o.y = f2h(a.y + bv.y + c.y + d.y);
    o.z = f2h(a.z + bv.z + c.z + d.z);
    o.w = f2h(a.w + bv.w + c.w + d.w);
    *(ushort4*)(ee + (size_t)be * DD + f) = o;
}

// ---------------------------------------------------------------------------
// Pack W [D][N] fp32 -> fp16 MFMA B-fragment order (3 weights in one launch)
//   pk ushort idx: ((nb*32 + kb)*64 + lane)*8 + j
//     = W[kb*32 + 8*(lane>>4) + j][nb*16 + (lane&15)]
// ---------------------------------------------------------------------------
__global__ __launch_bounds__(256) void pack_w_kernel(
    const float* __restrict__ W0, const float* __restrict__ W1f,
    const float* __restrict__ W2f, ushort* __restrict__ pk0,
    ushort* __restrict__ pk1, ushort* __restrict__ pk2) {
    const float* W = blockIdx.y == 0 ? W0 : (blockIdx.y == 1 ? W1f : W2f);
    ushort* pk     = blockIdx.y == 0 ? pk0 : (blockIdx.y == 1 ? pk1 : pk2);
    int idx = blockIdx.x * 256 + threadIdx.x;    // 0 .. 131071
    int l  = idx & 63;
    int kb = (idx >> 6) & 31;
    int nb = idx >> 11;
    int row = kb * 32 + (l >> 4) * 8;
    int col = nb * 16 + (l & 15);
    ushort o[8];
#pragma unroll
    for (int j = 0; j < 8; ++j)
        o[j] = f2h(W[(size_t)(row + j) * NHD + col]);
    ulong2 v;
    v.x = ((ulong)o[0]) | ((ulong)o[1] << 16) | ((ulong)o[2] << 32) | ((ulong)o[3] << 48);
    v.y = ((ulong)o[4]) | ((ulong)o[5] << 16) | ((ulong)o[6] << 32) | ((ulong)o[7] << 48);
    *(ulong2*)(pk + (size_t)idx * 8) = v;
}

// ---------------------------------------------------------------------------
// GEMM1 (LDS-tiled): fused[r,f] = fp16( ee[b,ci,:].Wc + ee[b,ti,:].Wt + bc + bt )
// Block 128x128, BK=32, 4 waves (2x2) x wave-tile 64x64 (4x4 16x16x32 frags).
// A staged into padded LDS (80B rows -> 2-way = free); B chunks stay in packed
// fragment order (linear, conflict-free). Next tile's globals prefetched
// before the MFMA block. Grid 240 = 30x8; by=bid&7 -> per-XCD col panel.
// ---------------------------------------------------------------------------
__global__ __launch_bounds__(256) void gemm1_kernel(
    const ushort* __restrict__ ee, const int* __restrict__ ci, const int* __restrict__ ti,
    const ushort* __restrict__ Wc_pk, const ushort* __restrict__ Wt_pk,
    const float* __restrict__ bc, const float* __restrict__ bt,
    ushort* __restrict__ fused) {
    __shared__ ushort As[128 * 40];   // row r at ushort r*40 (80B rows, 2-way free)
    __shared__ ushort Bs[8 * 512];    // 8 fragment chunks of 1KB

    int t = threadIdx.x;
    int l = t & 63;
    int w = t >> 6;
    int wm = w >> 1, wn = w & 1;
    int bx = blockIdx.x >> 3;         // 0..29
    int by = blockIdx.x & 7;          // 0..7 (XCD-local col panel)
    int row0 = bx * 128, col0 = by * 128;
    int nb0  = col0 >> 4;

    // A staging role: thread -> row sr, segs {ss, ss+2} of 8 fp16
    int sr = t >> 1;
    int ss = t & 1;
    int Rg = row0 + sr;
    int bq = Rg / NCOL, iq = Rg - bq * NCOL;
    const ushort* ap0 = ee + ((size_t)(bq * EE + ci[iq])) * DD;
    const ushort* ap1 = ee + ((size_t)(bq * EE + ti[iq])) * DD;

    f32x4 acc[4][4] = {};
    f16x8 av0, av1, bv0, bv1;

#define G1_LOAD(kb)                                                              \
    {                                                                            \
        int kk = (kb) & 31;                                                      \
        const ushort* ap = ((kb) >> 5) ? ap1 : ap0;                              \
        const ushort* Wp = ((kb) >> 5) ? Wt_pk : Wc_pk;                          \
        av0 = *(const f16x8*)(ap + kk * 32 + ss * 8);                            \
        av1 = *(const f16x8*)(ap + kk * 32 + (ss + 2) * 8);                      \
        bv0 = *(const f16x8*)(Wp + ((size_t)(nb0 + w) * 32 + kk) * 512 + l * 8); \
        bv1 = *(const f16x8*)(Wp + ((size_t)(nb0 + 4 + w) * 32 + kk) * 512 + l * 8); \
    }

    G1_LOAD(0)
#pragma unroll 1
    for (int kb = 0; kb < NKB1; ++kb) {
        __syncthreads();                       // previous step's ds_reads done
        *(f16x8*)&As[sr * 40 + ss * 8]       = av0;
        *(f16x8*)&As[sr * 40 + (ss + 2) * 8] = av1;
        *(f16x8*)&Bs[w * 512 + l * 8]        = bv0;
        *(f16x8*)&Bs[(4 + w) * 512 + l * 8]  = bv1;
        __syncthreads();                       // LDS tile ready
        int kbn = (kb + 1 < NKB1) ? kb + 1 : kb;
        G1_LOAD(kbn)                           // prefetch overlaps MFMA below
        f16x8 af[4], bf[4];
#pragma unroll
        for (int m = 0; m < 4; ++m)
            af[m] = *(const f16x8*)&As[(wm * 64 + m * 16 + (l & 15)) * 40 + (l >> 4) * 8];
#pragma unroll
        for (int n = 0; n < 4; ++n)
            bf[n] = *(const f16x8*)&Bs[(wn * 4 + n) * 512 + l * 8];
#pragma unroll
        for (int m = 0; m < 4; ++m)
#pragma unroll
            for (int n = 0; n < 4; ++n)
                acc[m][n] = __builtin_amdgcn_mfma_f32_16x16x32_f16(
                    af[m], bf[n], acc[m][n], 0, 0, 0);
    }
#undef G1_LOAD

    int lr = (l >> 4) * 4;
#pragma unroll
    for (int n = 0; n < 4; ++n) {
        int c = col0 + wn * 64 + n * 16 + (l & 15);
        float badd = bc[c] + bt[c];
#pragma unroll
        for (int m = 0; m < 4; ++m) {
            int rbase = row0 + wm * 64 + m * 16 + lr;
#pragma unroll
            for (int j = 0; j < 4; ++j)
                fused[(size_t)(rbase + j) * NHD + c] = f2h(acc[m][n][j] + badd);
        }
    }
}

// ---------------------------------------------------------------------------
// GEMM2 (LDS-tiled): h = relu(fused @ W_o1 + b_o1); att[r] += h . W_o2
// Same structure as GEMM1 (single phase, K=1024); h lives only in registers.
// ---------------------------------------------------------------------------
__global__ __launch_bounds__(256) void gemm2_kernel(
    const ushort* __restrict__ fused, const ushort* __restrict__ W1_pk,
    const float* __restrict__ b1, const float* __restrict__ W2,
    float* __restrict__ att) {
    __shared__ ushort As[128 * 40];
    __shared__ ushort Bs[8 * 512];

    int t = threadIdx.x;
    int l = t & 63;
    int w = t >> 6;
    int wm = w >> 1, wn = w & 1;
    int bx = blockIdx.x >> 3;
    int by = blockIdx.x & 7;
    int row0 = bx * 128, col0 = by * 128;
    int nb0  = col0 >> 4;

    int sr = t >> 1;
    int ss = t & 1;
    const ushort* ap = fused + (size_t)(row0 + sr) * NHD;

    f32x4 acc[4][4] = {};
    f16x8 av0, av1, bv0, bv1;

#define G2_LOAD(kb)                                                              \
    {                                                                            \
        int kk = (kb);                                                           \
        av0 = *(const f16x8*)(ap + kk * 32 + ss * 8);                            \
        av1 = *(const f16x8*)(ap + kk * 32 + (ss + 2) * 8);                      \
        bv0 = *(const f16x8*)(W1_pk + ((size_t)(nb0 + w) * 32 + kk) * 512 + l * 8); \
        bv1 = *(const f16x8*)(W1_pk + ((size_t)(nb0 + 4 + w) * 32 + kk) * 512 + l * 8); \
    }

    G2_LOAD(0)
#pragma unroll 1
    for (int kb = 0; kb < NKB2; ++kb) {
        __syncthreads();
        *(f16x8*)&As[sr * 40 + ss * 8]       = av0;
        *(f16x8*)&As[sr * 40 + (ss + 2) * 8] = av1;
        *(f16x8*)&Bs[w * 512 + l * 8]        = bv0;
        *(f16x8*)&Bs[(4 + w) * 512 + l * 8]  = bv1;
        __syncthreads();
        int kbn = (kb + 1 < NKB2) ? kb + 1 : kb;
        G2_LOAD(kbn)
        f16x8 af[4], bf[4];
#pragma unroll
        for (int m = 0; m < 4; ++m)
            af[m] = *(const f16x8*)&As[(wm * 64 + m * 16 + (l & 15)) * 40 + (l >> 4) * 8];
#pragma unroll
        for (int n = 0; n < 4; ++n)
            bf[n] = *(const f16x8*)&Bs[(wn * 4 + n) * 512 + l * 8];
#pragma unroll
        for (int m = 0; m < 4; ++m)
#pragma unroll
            for (int n = 0; n < 4; ++n)
                acc[m][n] = __builtin_amdgcn_mfma_f32_16x16x32_f16(
                    af[m], bf[n], acc[m][n], 0, 0, 0);
    }
#undef G2_LOAD

    float bo[4], wo[4];
#pragma unroll
    for (int n = 0; n < 4; ++n) {
        int c = col0 + wn * 64 + n * 16 + (l & 15);
        bo[n] = b1[c];
        wo[n] = W2[c];
    }
    int lr = (l >> 4) * 4;
#pragma unroll
    for (int m = 0; m < 4; ++m) {
#pragma unroll
        for (int j = 0; j < 4; ++j) {
            float p = 0.f;
#pragma unroll
            for (int n = 0; n < 4; ++n) {
                float h = fmaxf(acc[m][n][j] + bo[n], 0.f);
                p = fmaf(h, wo[n], p);
            }
            p += __shfl_xor(p, 1);
            p += __shfl_xor(p, 2);
            p += __shfl_xor(p, 4);
            p += __shfl_xor(p, 8);
            if ((l & 15) == 0)
                atomicAdd(&att[row0 + wm * 64 + m * 16 + lr + j], p);
        }
    }
}

// ---------------------------------------------------------------------------
// K5a: H[b,f] += cls[b, k-chunk] @ W_t1[k-chunk, f-chunk]   (fp32, atomics)
// ---------------------------------------------------------------------------
__global__ __launch_bounds__(256) void topk_h_kernel(const float* __restrict__ q,
                                                     const float* __restrict__ W1,
                                                     float* __restrict__ H) {
    __shared__ float cls[BB][128];
    __shared__ float wsh[128][17];
    int f0 = blockIdx.x * 16;
    int k0 = blockIdx.y * 128;
    int t = threadIdx.x;
#pragma unroll
    for (int m = 0; m < 16; ++m) {
        int idx = t + m * 256;              // 0..4095
        int b = idx >> 7, d = idx & 127;
        cls[b][d] = q[(size_t)b * LL * DD + k0 + d];
    }
#pragma unroll
    for (int m = 0; m < 8; ++m) {
        int idx = t + m * 256;              // 0..2047
        int r = idx >> 4, c = idx & 15;
        wsh[r][c] = W1[(size_t)(k0 + r) * NHD + f0 + c];
    }
    __syncthreads();
    int f = t & 15;
    int b0 = t >> 4;                        // 0..15
#pragma unroll
    for (int h = 0; h < 2; ++h) {
        int b = b0 + h * 16;
        float s = 0.f;
#pragma unroll 8
        for (int d = 0; d < 128; ++d)
            s = fmaf(cls[b][d], wsh[d][f], s);
        atomicAdd(&H[(size_t)b * NHD + f0 + f], s);
    }
}

// ---------------------------------------------------------------------------
// K5b: topk[b,:] = sigmoid(relu(H[b,:]) @ W_t2 + b_t2)
// ---------------------------------------------------------------------------
__global__ __launch_bounds__(256) void topk_out_kernel(
    const float* __restrict__ H, const float* __restrict__ W2,
    const float* __restrict__ b2, float* __restrict__ outp) {
    __shared__ float red[4][TOPKN];
    int b = blockIdx.x;
    int t = threadIdx.x;
    float part[TOPKN] = {};
#pragma unroll
    for (int m = 0; m < 4; ++m) {
        int f = t + m * 256;
        float h = fmaxf(H[(size_t)b * NHD + f], 0.f);
#pragma unroll
        for (int k = 0; k < TOPKN; ++k)
            part[k] = fmaf(h, W2[f * TOPKN + k], part[k]);
    }
#pragma unroll
    for (int k = 0; k < TOPKN; ++k) {
        float v = part[k];
        for (int off = 1; off < 64; off <<= 1) v += __shfl_xor(v, off);
        part[k] = v;
    }
    int wave = t >> 6, lane = t & 63;
    if (lane == 0)
#pragma unroll
        for (int k = 0; k < TOPKN; ++k) red[wave][k] = part[k];
    __syncthreads();
    if (t == 0)
#pragma unroll
        for (int k = 0; k < TOPKN; ++k) {
            float s = red[0][k] + red[1][k] + red[2][k] + red[3][k] + b2[k];
            outp[b * TOPKN + k] = 1.f / (1.f + __expf(-s));
        }
}

// ---------------------------------------------------------------------------
extern "C" void kernel_launch(void* const* d_in, const int* in_sizes, int n_in,
                              void* d_out, int out_size, void* d_ws, size_t ws_size,
                              hipStream_t stream) {
    const float* q_enc   = (const float*)d_in[0];
    const int*   etok    = (const int*)  d_in[1];
    const int*   ci      = (const int*)  d_in[2];
    const int*   ti      = (const int*)  d_in[3];
    const float* W_table = (const float*)d_in[4];
    const float* b_table = (const float*)d_in[5];
    const float* W_col   = (const float*)d_in[6];
    const float* b_col   = (const float*)d_in[7];
    const float* W_o1    = (const float*)d_in[8];
    const float* b_o1    = (const float*)d_in[9];
    const float* W_o2    = (const float*)d_in[10];
    const float* b_o2    = (const float*)d_in[11];
    const float* W_t1    = (const float*)d_in[12];
    const float* b_t1    = (const float*)d_in[13];
    const float* W_t2    = (const float*)d_in[14];
    const float* b_t2    = (const float*)d_in[15];

    float* outp = (float*)d_out;
    float* att  = outp;            // 3840
    float* topk = outp + MROWS;    // 192

    // workspace layout (bytes)
    char* ws = (char*)d_ws;
    ushort* ee_h    = (ushort*)(ws);                          // 4,194,304 fp16
    ushort* fused   = (ushort*)(ws + 8388608);                // 3,932,160 fp16
    ushort* Wc_pk   = (ushort*)(ws + 16252928);               // 1,048,576 fp16
    ushort* Wt_pk   = (ushort*)(ws + 18350080);               // 1,048,576 fp16
    ushort* Wo1_pk  = (ushort*)(ws + 20447232);               // 1,048,576 fp16
    float*  H       = (float*) (ws + 22544384);               // 32,768 f32

    hipLaunchKernelGGL(ee_kernel, dim3(BB * EE), dim3(256), 0, stream,
                       q_enc, etok, ee_h, att, b_o2, H, b_t1);
    hipLaunchKernelGGL(pack_w_kernel, dim3(512, 3), dim3(256), 0, stream,
                       W_col, W_table, W_o1, Wc_pk, Wt_pk, Wo1_pk);
    hipLaunchKernelGGL(gemm1_kernel, dim3((MROWS / 128) * (NHD / 128)), dim3(256), 0, stream,
                       ee_h, ci, ti, Wc_pk, Wt_pk, b_col, b_table, fused);
    hipLaunchKernelGGL(gemm2_kernel, dim3((MROWS / 128) * (NHD / 128)), dim3(256), 0, stream,
                       fused, Wo1_pk, b_o1, W_o2, att);
    hipLaunchKernelGGL(topk_h_kernel, dim3(64, 8), dim3(256), 0, stream, q_enc, W_t1, H);
    hipLaunchKernelGGL(topk_out_kernel, dim3(BB), dim3(256), 0, stream, H, W_t2, b_t2, topk);
}

// Round 14
// 197.329 us; speedup vs baseline: 1.1817x; 1.0938x over previous
//
#include <hip/hip_runtime.h>
#include <hip/hip_bf16.h>

#define BB 32
#define LL 512
#define DD 1024
#define NHD 1024
#define EE 128
#define NCOL 120
#define KTOK 4
#define TOPKN 6
#define MROWS (BB * NCOL)   // 3840
#define NKB1 64             // gemm1 K-steps (2 phases x 32)
#define NKB2 32             // gemm2 K-steps

typedef __attribute__((ext_vector_type(8))) _Float16 f16x8;
typedef __attribute__((ext_vector_type(4))) float f32x4;

__device__ inline ushort f2h(float x) {
    _Float16 h = (_Float16)x;              // RNE via v_cvt_f16_f32
    union { _Float16 h; ushort u; } c;
    c.h = h;
    return c.u;
}

// ---------------------------------------------------------------------------
// K1: ee_h[b,e,:] = fp16( sum_k q_enc[b, tok[e,k], :] )  + folded init duty
// ---------------------------------------------------------------------------
__global__ __launch_bounds__(256) void ee_kernel(const float* __restrict__ q,
                                                 const int* __restrict__ tok,
                                                 ushort* __restrict__ ee,
                                                 float* __restrict__ att,
                                                 const float* __restrict__ b_o2,
                                                 float* __restrict__ H,
                                                 const float* __restrict__ b_t1) {
    int be = blockIdx.x;
    int b  = be >> 7;
    int e  = be & 127;
    int t  = threadIdx.x;

    if (be < 15) {
        att[be * 256 + t] = b_o2[0];
    } else if (be < 15 + 128) {
        int j = (be - 15) * 256 + t;
        H[j] = b_t1[j & (NHD - 1)];
    }

    const float* qb = q + (size_t)b * LL * DD;
    int t0 = tok[e * KTOK + 0];
    int t1 = tok[e * KTOK + 1];
    int t2 = tok[e * KTOK + 2];
    int t3 = tok[e * KTOK + 3];
    int f = t * 4;
    float4 a = *(const float4*)(qb + (size_t)t0 * DD + f);
    float4 bv = *(const float4*)(qb + (size_t)t1 * DD + f);
    float4 c = *(const float4*)(qb + (size_t)t2 * DD + f);
    float4 d = *(const float4*)(qb + (size_t)t3 * DD + f);
    ushort4 o;
    o.x = f2h(a.x + bv.x + c.x + d.x);
    o.y = f2h(a.y + bv.y + c.y + d.y);
    o.z = f2h(a.z + bv.z + c.z + d.z);
    o.w = f2h(a.w + bv.w + c.w + d.w);
    *(ushort4*)(ee + (size_t)be * DD + f) = o;
}

// ---------------------------------------------------------------------------
// Pack W [D][N] fp32 -> fp16 MFMA B-fragment order (3 weights in one launch)
//   pk ushort idx: ((nb*32 + kb)*64 + lane)*8 + j
//     = W[kb*32 + 8*(lane>>4) + j][nb*16 + (lane&15)]
// ---------------------------------------------------------------------------
__global__ __launch_bounds__(256) void pack_w_kernel(
    const float* __restrict__ W0, const float* __restrict__ W1f,
    const float* __restrict__ W2f, ushort* __restrict__ pk0,
    ushort* __restrict__ pk1, ushort* __restrict__ pk2) {
    const float* W = blockIdx.y == 0 ? W0 : (blockIdx.y == 1 ? W1f : W2f);
    ushort* pk     = blockIdx.y == 0 ? pk0 : (blockIdx.y == 1 ? pk1 : pk2);
    int idx = blockIdx.x * 256 + threadIdx.x;    // 0 .. 131071
    int l  = idx & 63;
    int kb = (idx >> 6) & 31;
    int nb = idx >> 11;
    int row = kb * 32 + (l >> 4) * 8;
    int col = nb * 16 + (l & 15);
    ushort o[8];
#pragma unroll
    for (int j = 0; j < 8; ++j)
        o[j] = f2h(W[(size_t)(row + j) * NHD + col]);
    ulong2 v;
    v.x = ((ulong)o[0]) | ((ulong)o[1] << 16) | ((ulong)o[2] << 32) | ((ulong)o[3] << 48);
    v.y = ((ulong)o[4]) | ((ulong)o[5] << 16) | ((ulong)o[6] << 32) | ((ulong)o[7] << 48);
    *(ulong2*)(pk + (size_t)idx * 8) = v;
}

// ---------------------------------------------------------------------------
// GEMM1: 64x64 tile, BK=32, 4 waves (2x2) x wave-tile 32x32.
// A double-buffered in LDS (1 barrier/step); B read DIRECT from packed
// fragments into depth-2 register stages (L2-resident via XCD col pinning).
// Grid 60x16 = 960 blocks (~3.75/CU) -> cross-block overlap hides drains.
// ---------------------------------------------------------------------------
__global__ __launch_bounds__(256) void gemm1_kernel(
    const ushort* __restrict__ ee, const int* __restrict__ ci, const int* __restrict__ ti,
    const ushort* __restrict__ Wc_pk, const ushort* __restrict__ Wt_pk,
    const float* __restrict__ bc, const float* __restrict__ bt,
    ushort* __restrict__ fused) {
    __shared__ ushort As0[64 * 40];    // row stride 40 ushorts (2-way ~ free)
    __shared__ ushort As1[64 * 40];

    int t = threadIdx.x;
    int l = t & 63;
    int w = t >> 6;
    int wm = w >> 1, wn = w & 1;
    int bx = blockIdx.x >> 4;          // 0..59
    int by = blockIdx.x & 15;          // 0..15 -> XCD = by&7 (col panel pinned)
    int row0 = bx * 64, col0 = by * 64;
    int nbw  = (col0 >> 4) + wn * 2;   // this wave's first B chunk
    int koff = (l >> 4) * 8;

    // A staging role: thread t -> row t>>2, seg t&3 (8 ushorts)
    int arow = t >> 2;
    int seg  = t & 3;
    int Rg = row0 + arow;
    int bq = Rg / NCOL, iq = Rg - bq * NCOL;
    const ushort* ap0 = ee + ((size_t)(bq * EE + ci[iq])) * DD;
    const ushort* ap1 = ee + ((size_t)(bq * EE + ti[iq])) * DD;

    f32x4 acc00 = {}, acc01 = {}, acc10 = {}, acc11 = {};
    f16x8 sA, ba0, ba1, bb0, bb1;

#define LOADA(S, kb)                                                             \
    {                                                                            \
        int kk = (kb) & 31;                                                      \
        const ushort* ap = ((kb) >> 5) ? ap1 : ap0;                              \
        S = *(const f16x8*)(ap + kk * 32 + seg * 8);                             \
    }
#define LOADB(B0, B1, kb)                                                        \
    {                                                                            \
        int kk = (kb) & 31;                                                      \
        const ushort* Wp = ((kb) >> 5) ? Wt_pk : Wc_pk;                          \
        B0 = *(const f16x8*)(Wp + ((size_t)nbw * 32 + kk) * 512 + l * 8);        \
        B1 = *(const f16x8*)(Wp + ((size_t)(nbw + 1) * 32 + kk) * 512 + l * 8);  \
    }
#define WRITEA(BUF, S) { *(f16x8*)&BUF[arow * 40 + seg * 8] = S; }
#define COMP(BUF, B0, B1)                                                        \
    {                                                                            \
        f16x8 a0 = *(const f16x8*)&BUF[(wm * 32 + (l & 15)) * 40 + koff];        \
        f16x8 a1 = *(const f16x8*)&BUF[(wm * 32 + 16 + (l & 15)) * 40 + koff];   \
        acc00 = __builtin_amdgcn_mfma_f32_16x16x32_f16(a0, B0, acc00, 0, 0, 0);  \
        acc01 = __builtin_amdgcn_mfma_f32_16x16x32_f16(a0, B1, acc01, 0, 0, 0);  \
        acc10 = __builtin_amdgcn_mfma_f32_16x16x32_f16(a1, B0, acc10, 0, 0, 0);  \
        acc11 = __builtin_amdgcn_mfma_f32_16x16x32_f16(a1, B1, acc11, 0, 0, 0);  \
    }

    LOADA(sA, 0)
    WRITEA(As0, sA)
    LOADA(sA, 1)
    LOADB(ba0, ba1, 0)
    LOADB(bb0, bb1, 1)
    __syncthreads();

#pragma unroll 1
    for (int kb = 0; kb < NKB1; kb += 2) {
        WRITEA(As1, sA)                               // tile kb+1 -> LDS
        { int kn = kb + 2 < NKB1 ? kb + 2 : NKB1 - 1; LOADA(sA, kn) }
        COMP(As0, ba0, ba1)                           // compute tile kb
        { int kn = kb + 2 < NKB1 ? kb + 2 : NKB1 - 1; LOADB(ba0, ba1, kn) }
        __syncthreads();
        WRITEA(As0, sA)                               // tile kb+2 -> LDS
        { int kn = kb + 3 < NKB1 ? kb + 3 : NKB1 - 1; LOADA(sA, kn) }
        COMP(As1, bb0, bb1)                           // compute tile kb+1
        { int kn = kb + 3 < NKB1 ? kb + 3 : NKB1 - 1; LOADB(bb0, bb1, kn) }
        __syncthreads();
    }
#undef LOADA
#undef LOADB
#undef WRITEA
#undef COMP

    int lr = (l >> 4) * 4;
    f32x4 accm[2][2] = {{acc00, acc01}, {acc10, acc11}};
#pragma unroll
    for (int n = 0; n < 2; ++n) {
        int c = col0 + wn * 32 + n * 16 + (l & 15);
        float badd = bc[c] + bt[c];
#pragma unroll
        for (int m = 0; m < 2; ++m) {
            int rbase = row0 + wm * 32 + m * 16 + lr;
#pragma unroll
            for (int j = 0; j < 4; ++j)
                fused[(size_t)(rbase + j) * NHD + c] = f2h(accm[m][n][j] + badd);
        }
    }
}

// ---------------------------------------------------------------------------
// GEMM2: h = relu(fused @ W_o1 + b_o1); att[r] += h . W_o2  (h in regs only)
// Same structure; single K phase; fused epilogue.
// ---------------------------------------------------------------------------
__global__ __launch_bounds__(256) void gemm2_kernel(
    const ushort* __restrict__ fused, const ushort* __restrict__ W1_pk,
    const float* __restrict__ b1, const float* __restrict__ W2,
    float* __restrict__ att) {
    __shared__ ushort As0[64 * 40];
    __shared__ ushort As1[64 * 40];

    int t = threadIdx.x;
    int l = t & 63;
    int w = t >> 6;
    int wm = w >> 1, wn = w & 1;
    int bx = blockIdx.x >> 4;
    int by = blockIdx.x & 15;
    int row0 = bx * 64, col0 = by * 64;
    int nbw  = (col0 >> 4) + wn * 2;
    int koff = (l >> 4) * 8;

    int arow = t >> 2;
    int seg  = t & 3;
    const ushort* ap = fused + (size_t)(row0 + arow) * NHD;

    f32x4 acc00 = {}, acc01 = {}, acc10 = {}, acc11 = {};
    f16x8 sA, ba0, ba1, bb0, bb1;

#define LOADA(S, kb)  { S = *(const f16x8*)(ap + (kb) * 32 + seg * 8); }
#define LOADB(B0, B1, kb)                                                        \
    {                                                                            \
        B0 = *(const f16x8*)(W1_pk + ((size_t)nbw * 32 + (kb)) * 512 + l * 8);   \
        B1 = *(const f16x8*)(W1_pk + ((size_t)(nbw + 1) * 32 + (kb)) * 512 + l * 8); \
    }
#define WRITEA(BUF, S) { *(f16x8*)&BUF[arow * 40 + seg * 8] = S; }
#define COMP(BUF, B0, B1)                                                        \
    {                                                                            \
        f16x8 a0 = *(const f16x8*)&BUF[(wm * 32 + (l & 15)) * 40 + koff];        \
        f16x8 a1 = *(const f16x8*)&BUF[(wm * 32 + 16 + (l & 15)) * 40 + koff];   \
        acc00 = __builtin_amdgcn_mfma_f32_16x16x32_f16(a0, B0, acc00, 0, 0, 0);  \
        acc01 = __builtin_amdgcn_mfma_f32_16x16x32_f16(a0, B1, acc01, 0, 0, 0);  \
        acc10 = __builtin_amdgcn_mfma_f32_16x16x32_f16(a1, B0, acc10, 0, 0, 0);  \
        acc11 = __builtin_amdgcn_mfma_f32_16x16x32_f16(a1, B1, acc11, 0, 0, 0);  \
    }

    LOADA(sA, 0)
    WRITEA(As0, sA)
    LOADA(sA, 1)
    LOADB(ba0, ba1, 0)
    LOADB(bb0, bb1, 1)
    __syncthreads();

#pragma unroll 1
    for (int kb = 0; kb < NKB2; kb += 2) {
        WRITEA(As1, sA)
        { int kn = kb + 2 < NKB2 ? kb + 2 : NKB2 - 1; LOADA(sA, kn) }
        COMP(As0, ba0, ba1)
        { int kn = kb + 2 < NKB2 ? kb + 2 : NKB2 - 1; LOADB(ba0, ba1, kn) }
        __syncthreads();
        WRITEA(As0, sA)
        { int kn = kb + 3 < NKB2 ? kb + 3 : NKB2 - 1; LOADA(sA, kn) }
        COMP(As1, bb0, bb1)
        { int kn = kb + 3 < NKB2 ? kb + 3 : NKB2 - 1; LOADB(bb0, bb1, kn) }
        __syncthreads();
    }
#undef LOADA
#undef LOADB
#undef WRITEA
#undef COMP

    float bo[2], wo[2];
#pragma unroll
    for (int n = 0; n < 2; ++n) {
        int c = col0 + wn * 32 + n * 16 + (l & 15);
        bo[n] = b1[c];
        wo[n] = W2[c];
    }
    int lr = (l >> 4) * 4;
    f32x4 accm[2][2] = {{acc00, acc01}, {acc10, acc11}};
#pragma unroll
    for (int m = 0; m < 2; ++m) {
#pragma unroll
        for (int j = 0; j < 4; ++j) {
            float p = 0.f;
#pragma unroll
            for (int n = 0; n < 2; ++n) {
                float h = fmaxf(accm[m][n][j] + bo[n], 0.f);
                p = fmaf(h, wo[n], p);
            }
            p += __shfl_xor(p, 1);
            p += __shfl_xor(p, 2);
            p += __shfl_xor(p, 4);
            p += __shfl_xor(p, 8);
            if ((l & 15) == 0)
                atomicAdd(&att[row0 + wm * 32 + m * 16 + lr + j], p);
        }
    }
}

// ---------------------------------------------------------------------------
// K5a: H[b,f] += cls[b, k-chunk] @ W_t1[k-chunk, f-chunk]   (fp32, atomics)
// ---------------------------------------------------------------------------
__global__ __launch_bounds__(256) void topk_h_kernel(const float* __restrict__ q,
                                                     const float* __restrict__ W1,
                                                     float* __restrict__ H) {
    __shared__ float cls[BB][128];
    __shared__ float wsh[128][17];
    int f0 = blockIdx.x * 16;
    int k0 = blockIdx.y * 128;
    int t = threadIdx.x;
#pragma unroll
    for (int m = 0; m < 16; ++m) {
        int idx = t + m * 256;              // 0..4095
        int b = idx >> 7, d = idx & 127;
        cls[b][d] = q[(size_t)b * LL * DD + k0 + d];
    }
#pragma unroll
    for (int m = 0; m < 8; ++m) {
        int idx = t + m * 256;              // 0..2047
        int r = idx >> 4, c = idx & 15;
        wsh[r][c] = W1[(size_t)(k0 + r) * NHD + f0 + c];
    }
    __syncthreads();
    int f = t & 15;
    int b0 = t >> 4;                        // 0..15
#pragma unroll
    for (int h = 0; h < 2; ++h) {
        int b = b0 + h * 16;
        float s = 0.f;
#pragma unroll 8
        for (int d = 0; d < 128; ++d)
            s = fmaf(cls[b][d], wsh[d][f], s);
        atomicAdd(&H[(size_t)b * NHD + f0 + f], s);
    }
}

// ---------------------------------------------------------------------------
// K5b: topk[b,:] = sigmoid(relu(H[b,:]) @ W_t2 + b_t2)
// ---------------------------------------------------------------------------
__global__ __launch_bounds__(256) void topk_out_kernel(
    const float* __restrict__ H, const float* __restrict__ W2,
    const float* __restrict__ b2, float* __restrict__ outp) {
    __shared__ float red[4][TOPKN];
    int b = blockIdx.x;
    int t = threadIdx.x;
    float part[TOPKN] = {};
#pragma unroll
    for (int m = 0; m < 4; ++m) {
        int f = t + m * 256;
        float h = fmaxf(H[(size_t)b * NHD + f], 0.f);
#pragma unroll
        for (int k = 0; k < TOPKN; ++k)
            part[k] = fmaf(h, W2[f * TOPKN + k], part[k]);
    }
#pragma unroll
    for (int k = 0; k < TOPKN; ++k) {
        float v = part[k];
        for (int off = 1; off < 64; off <<= 1) v += __shfl_xor(v, off);
        part[k] = v;
    }
    int wave = t >> 6, lane = t & 63;
    if (lane == 0)
#pragma unroll
        for (int k = 0; k < TOPKN; ++k) red[wave][k] = part[k];
    __syncthreads();
    if (t == 0)
#pragma unroll
        for (int k = 0; k < TOPKN; ++k) {
            float s = red[0][k] + red[1][k] + red[2][k] + red[3][k] + b2[k];
            outp[b * TOPKN + k] = 1.f / (1.f + __expf(-s));
        }
}

// ---------------------------------------------------------------------------
extern "C" void kernel_launch(void* const* d_in, const int* in_sizes, int n_in,
                              void* d_out, int out_size, void* d_ws, size_t ws_size,
                              hipStream_t stream) {
    const float* q_enc   = (const float*)d_in[0];
    const int*   etok    = (const int*)  d_in[1];
    const int*   ci      = (const int*)  d_in[2];
    const int*   ti      = (const int*)  d_in[3];
    const float* W_table = (const float*)d_in[4];
    const float* b_table = (const float*)d_in[5];
    const float* W_col   = (const float*)d_in[6];
    const float* b_col   = (const float*)d_in[7];
    const float* W_o1    = (const float*)d_in[8];
    const float* b_o1    = (const float*)d_in[9];
    const float* W_o2    = (const float*)d_in[10];
    const float* b_o2    = (const float*)d_in[11];
    const float* W_t1    = (const float*)d_in[12];
    const float* b_t1    = (const float*)d_in[13];
    const float* W_t2    = (const float*)d_in[14];
    const float* b_t2    = (const float*)d_in[15];

    float* outp = (float*)d_out;
    float* att  = outp;            // 3840
    float* topk = outp + MROWS;    // 192

    // workspace layout (bytes)
    char* ws = (char*)d_ws;
    ushort* ee_h    = (ushort*)(ws);                          // 4,194,304 fp16
    ushort* fused   = (ushort*)(ws + 8388608);                // 3,932,160 fp16
    ushort* Wc_pk   = (ushort*)(ws + 16252928);               // 1,048,576 fp16
    ushort* Wt_pk   = (ushort*)(ws + 18350080);               // 1,048,576 fp16
    ushort* Wo1_pk  = (ushort*)(ws + 20447232);               // 1,048,576 fp16
    float*  H       = (float*) (ws + 22544384);               // 32,768 f32

    hipLaunchKernelGGL(ee_kernel, dim3(BB * EE), dim3(256), 0, stream,
                       q_enc, etok, ee_h, att, b_o2, H, b_t1);
    hipLaunchKernelGGL(pack_w_kernel, dim3(512, 3), dim3(256), 0, stream,
                       W_col, W_table, W_o1, Wc_pk, Wt_pk, Wo1_pk);
    hipLaunchKernelGGL(gemm1_kernel, dim3((MROWS / 64) * (NHD / 64)), dim3(256), 0, stream,
                       ee_h, ci, ti, Wc_pk, Wt_pk, b_col, b_table, fused);
    hipLaunchKernelGGL(gemm2_kernel, dim3((MROWS / 64) * (NHD / 64)), dim3(256), 0, stream,
                       fused, Wo1_pk, b_o1, W_o2, att);
    hipLaunchKernelGGL(topk_h_kernel, dim3(64, 8), dim3(256), 0, stream, q_enc, W_t1, H);
    hipLaunchKernelGGL(topk_out_kernel, dim3(BB), dim3(256), 0, stream, H, W_t2, b_t2, topk);
}